// Round 6
// baseline (9035.098 us; speedup 1.0000x reference)
//
#include <hip/hip_runtime.h>
#include <hip/hip_bf16.h>

// LSTM encoder: B=64, T=2048, D=256, H=512.
// Persistent-RNN: 128 wgs (1/CU via ~156KB LDS), each owns a [768 x 64] bf16
// slice of [U;W] in LDS.
//
// Tagged-u64 dataflow sync: h exchanged as (bf16 h0|h1<<16)<<32 | step_tag
// u64 words; consumers poll the data words until tag == t-1 (the polling
// load IS the data load). WAR safety: slot t&1 only ever holds tags {t,t-2}
// while polled for t, inductively.
//
// ROUND-6 SINGLE DELTA vs round 5 (7396us): EARLY POLL ROUND. At the step
// tail (just BEFORE the publish store), issue the 16 poll loads for the next
// step's tag. At the next step's head, after acc_x (LDS-only cover), the
// pre-check retires them at vmcnt(1) -- they are >1500cy old (free), and the
// younger publish store stays in flight (order pinned by a memory clobber
// between polls and store, so pre-check never waits on our own store ack).
// Words from on-pace-or-ahead peers hit the pre-check; the fresh spin (R5's
// loop, unchanged) handles only stragglers. Overlaps the MALL visibility RT
// with the loop tail+head; stragglers' early polls always hit, compressing
// the jitter cascade. Own-slice lanes (polls pre-date own publish) self-heal
// via one fresh round. Everything else byte-identical to round 5.

#define B_   64
#define T_   2048
#define D_   256
#define H_   512
#define G4   2048          // 4H
#define KK   24            // (H+D)/32
#define TILES 4            // B/16
#define UWP  40            // UWL row length (bf16 elems), 32 + 8 pad
#define BSTR (64 * UWP)    // UWL kk-slab stride in elems

#define OFF_UWL 0
#define SZ_UWL  (KK * 64 * UWP * 2)          // 122880
#define OFF_ZH  (OFF_UWL + SZ_UWL)           // 122880
#define SZ_ZH   (16 * 512 * 2)               // 16384 (h, XOR-swizzled)
#define OFF_ZX  (OFF_ZH + SZ_ZH)             // 139264
#define SZ_ZX   (2 * 16 * 256 * 2)           // 16384 (x, double-buffered, swz)
#define OFF_GT  (OFF_ZX + SZ_ZX)             // 155648
#define SZ_GT   (4 * 16 * 17 * 4)            // 4352
#define OFF_BS  (OFF_GT + SZ_GT)             // 160000
#define SZ_BS   (64 * 4)                     // 256
#define SMEM_BYTES (OFF_BS + SZ_BS)          // 160256 <= 163840

typedef __attribute__((ext_vector_type(8))) short v8s;
typedef __attribute__((ext_vector_type(4))) float v4f;
typedef unsigned long long u64;

__device__ __forceinline__ unsigned short f2bf(float f) {
    unsigned u = __builtin_bit_cast(unsigned, f);
    u = (u + 0x7FFFu + ((u >> 16) & 1u)) >> 16;   // RTNE
    return (unsigned short)u;
}
__device__ __forceinline__ u64 pack4(float4 v) {
    return (u64)((unsigned)f2bf(v.x) | ((unsigned)f2bf(v.y) << 16)) |
           ((u64)((unsigned)f2bf(v.z) | ((unsigned)f2bf(v.w) << 16)) << 32);
}
__device__ __forceinline__ float fast_sigmoid(float v) {
    return 1.0f / (1.0f + __expf(-v));
}
__device__ __forceinline__ float fast_tanh(float v) {
    float x = fminf(fmaxf(v, -15.0f), 15.0f);
    float e = __expf(2.0f * x);
    return (e - 1.0f) / (e + 1.0f);
}

__global__ void __launch_bounds__(256, 1)
lstm_persist(const float* __restrict__ x, const float* __restrict__ W,
             const float* __restrict__ U, const float* __restrict__ bias,
             float* __restrict__ out, u64* __restrict__ hbuf /* [2][64][256] */)
{
    extern __shared__ char smem[];
    unsigned short* UWL = (unsigned short*)(smem + OFF_UWL); // [KK][64][UWP]
    char*           zhB = smem + OFF_ZH;                     // [16][1024B] swz
    char*           zxB = smem + OFF_ZX;                     // [2][16][512B] swz
    float*          gt  = (float*)(smem + OFF_GT);           // [4][16][17]
    float*          bs  = (float*)(smem + OFF_BS);           // [64]

    const int tid  = threadIdx.x;
    const int g    = blockIdx.x;
    const int tile = g & (TILES - 1);   // batch tile 0..3 (16 batches)
    const int s    = g >> 2;            // h-slice 0..31 (16 h-cols)
    const int l    = tid & 63;
    const int w    = tid >> 6;          // wave 0..3 == gate index
    const int pb   = tid >> 4;          // pointwise: batch row 0..15
    const int jj   = tid & 15;          // pointwise: h col 0..15

    // ---- one-time: stage [U;W] slice (bf16) + bias into LDS ----
    for (int idx = tid; idx < (H_ + D_) * 64; idx += 256) {
        int k = idx >> 6;          // 0..767
        int n = idx & 63;          // local gate col
        int gcol = (n >> 4) * H_ + s * 16 + (n & 15);
        float v = (k < H_) ? U[(size_t)k * G4 + gcol]
                           : W[(size_t)(k - H_) * G4 + gcol];
        UWL[((k >> 5) * 64 + n) * UWP + (k & 31)] = f2bf(v);
    }
    if (tid < 64) {
        int gcol = (tid >> 4) * H_ + s * 16 + (tid & 15);
        bs[tid] = bias[gcol];
    }
    // zero zh for t=0
    for (int n = tid; n < 2048; n += 256)
        *(u64*)(zhB + n * 8) = 0ull;
    // stage x(t=0) -> zx[0] (swizzled)
    #pragma unroll
    for (int p = 0; p < 4; ++p) {
        int n = p * 256 + tid;          // 16 rows x 64 u64
        int row = n >> 6, c4 = n & 63;
        float4 v = *(const float4*)(x + ((size_t)(tile * 16 + row) * T_ + 0) * D_ + c4 * 4);
        *(u64*)(zxB + row * 512 + ((c4 * 8) ^ ((row & 7) << 4))) = pack4(v);
    }

    // ---- per-lane fragment offsets (XOR-swizzle folded into bases) ----
    const int r    = l & 15;            // a-frag row
    const int q    = l >> 4;            // a-frag k-quad
    const int krot = (r >> 2) & 1;
    const int qx   = (q ^ (r & 3)) << 4;
    const int ahoff0 = r * 1024 + qx + 64 * krot;        // even kk
    const int ahoff1 = r * 1024 + qx + 64 * (krot ^ 1);  // odd kk
    const int axoff0 = r * 512  + qx + 64 * krot;
    const int axoff1 = r * 512  + qx + 64 * (krot ^ 1);
    const unsigned short* brow = UWL + (w * 16 + r) * UWP + q * 8;

    u64 hv[16];              // tagged poll values; live across the back-edge
    float creg = 0.0f;       // cell state for (pb, jj) — thread-private
    __syncthreads();

    for (int t = 0; t < T_; ++t) {
        u64* hb = hbuf + (size_t)((t - 1) & 1) * 16384 + (size_t)tile * 4096;

        // ---- 1. acc_x = x_t @ Wslice (8 MFMAs, zx[t&1]; LDS-only, covers
        //         the early-poll retirement — no vmem waits in here) ----
        const char* axb = zxB + (t & 1) * 8192;
        v4f xc0 = {0,0,0,0}, xc1 = {0,0,0,0}, xc2 = {0,0,0,0}, xc3 = {0,0,0,0};
        {
            v8s a0 = *(const v8s*)(axb + axoff0 + 0);
            v8s b0 = *(const v8s*)(brow + (size_t)16 * BSTR);
            xc0 = __builtin_amdgcn_mfma_f32_16x16x32_bf16(a0, b0, xc0, 0, 0, 0);
            v8s a1 = *(const v8s*)(axb + axoff1 + 0);
            v8s b1 = *(const v8s*)(brow + (size_t)17 * BSTR);
            xc1 = __builtin_amdgcn_mfma_f32_16x16x32_bf16(a1, b1, xc1, 0, 0, 0);
            v8s a2 = *(const v8s*)(axb + axoff0 + 128);
            v8s b2 = *(const v8s*)(brow + (size_t)18 * BSTR);
            xc2 = __builtin_amdgcn_mfma_f32_16x16x32_bf16(a2, b2, xc2, 0, 0, 0);
            v8s a3 = *(const v8s*)(axb + axoff1 + 128);
            v8s b3 = *(const v8s*)(brow + (size_t)19 * BSTR);
            xc3 = __builtin_amdgcn_mfma_f32_16x16x32_bf16(a3, b3, xc3, 0, 0, 0);
            v8s a4 = *(const v8s*)(axb + axoff0 + 256);
            v8s b4 = *(const v8s*)(brow + (size_t)20 * BSTR);
            xc0 = __builtin_amdgcn_mfma_f32_16x16x32_bf16(a4, b4, xc0, 0, 0, 0);
            v8s a5 = *(const v8s*)(axb + axoff1 + 256);
            v8s b5 = *(const v8s*)(brow + (size_t)21 * BSTR);
            xc1 = __builtin_amdgcn_mfma_f32_16x16x32_bf16(a5, b5, xc1, 0, 0, 0);
            v8s a6 = *(const v8s*)(axb + axoff0 + 384);
            v8s b6 = *(const v8s*)(brow + (size_t)22 * BSTR);
            xc2 = __builtin_amdgcn_mfma_f32_16x16x32_bf16(a6, b6, xc2, 0, 0, 0);
            v8s a7 = *(const v8s*)(axb + axoff1 + 384);
            v8s b7 = *(const v8s*)(brow + (size_t)23 * BSTR);
            xc3 = __builtin_amdgcn_mfma_f32_16x16x32_bf16(a7, b7, xc3, 0, 0, 0);
        }

        // ---- 2. pre-check early polls (issued last step tail, ~retired);
        //         fresh-issue only pending; spin; unpack -> zh ----
        if (t > 0) {
            const unsigned tg = (unsigned)(t - 1);
            unsigned pend = 0u;
            #pragma unroll
            for (int p = 0; p < 16; ++p)
                pend |= ((unsigned)hv[p] != tg) ? (1u << p) : 0u;
            while (pend) {
                #pragma unroll
                for (int p = 0; p < 16; ++p)
                    if (pend & (1u << p))
                        hv[p] = __hip_atomic_load(hb + p * 256 + tid,
                                    __ATOMIC_RELAXED, __HIP_MEMORY_SCOPE_AGENT);
                unsigned np = 0u;
                #pragma unroll
                for (int p = 0; p < 16; ++p)
                    np |= ((unsigned)hv[p] != tg) ? (1u << p) : 0u;
                pend = np;
            }
            // zh dword writes: row p, colpair tid; 2-way max (free)
            #pragma unroll
            for (int p = 0; p < 16; ++p) {
                int swz = (p & 7) << 4;
                *(unsigned*)(zhB + p * 1024 + ((tid * 4) ^ swz)) =
                    (unsigned)(hv[p] >> 32);
            }
        }

        // ---- 3. issue x_{t+1} loads (post-spin: never drained by repolls;
        //         consumed at stage-zx behind barrier A + acc_h) ----
        float4 xr[4];
        if (t < T_ - 1) {
            #pragma unroll
            for (int p = 0; p < 4; ++p) {
                int n = p * 256 + tid, row = n >> 6, c4 = n & 63;
                xr[p] = *(const float4*)
                    (x + ((size_t)(tile * 16 + row) * T_ + (t + 1)) * D_ + c4 * 4);
            }
        }
        __syncthreads();   // (A) zh ready

        // ---- 4. acc_h = h_{t-1} @ Uslice (16 MFMAs, slabs 0..15) ----
        v4f ac0 = {0,0,0,0}, ac1 = {0,0,0,0}, ac2 = {0,0,0,0}, ac3 = {0,0,0,0};
        #pragma unroll
        for (int kk = 0; kk < 16; kk += 4) {
            v8s a0 = *(const v8s*)(zhB + ahoff0 + 128 * (kk >> 1));
            v8s b0 = *(const v8s*)(brow + (size_t)(kk + 0) * BSTR);
            ac0 = __builtin_amdgcn_mfma_f32_16x16x32_bf16(a0, b0, ac0, 0, 0, 0);
            v8s a1 = *(const v8s*)(zhB + ahoff1 + 128 * (kk >> 1));
            v8s b1 = *(const v8s*)(brow + (size_t)(kk + 1) * BSTR);
            ac1 = __builtin_amdgcn_mfma_f32_16x16x32_bf16(a1, b1, ac1, 0, 0, 0);
            v8s a2 = *(const v8s*)(zhB + ahoff0 + 128 * (kk >> 1) + 128);
            v8s b2 = *(const v8s*)(brow + (size_t)(kk + 2) * BSTR);
            ac2 = __builtin_amdgcn_mfma_f32_16x16x32_bf16(a2, b2, ac2, 0, 0, 0);
            v8s a3 = *(const v8s*)(zhB + ahoff1 + 128 * (kk >> 1) + 128);
            v8s b3 = *(const v8s*)(brow + (size_t)(kk + 3) * BSTR);
            ac3 = __builtin_amdgcn_mfma_f32_16x16x32_bf16(a3, b3, ac3, 0, 0, 0);
        }

        // ---- 5. stage x_{t+1} -> zx[(t+1)&1] (xr latency covered by 4) ----
        if (t < T_ - 1) {
            char* zxn = zxB + ((t + 1) & 1) * 8192;
            #pragma unroll
            for (int p = 0; p < 4; ++p) {
                int n = p * 256 + tid, row = n >> 6, c4 = n & 63;
                *(u64*)(zxn + row * 512 + ((c4 * 8) ^ ((row & 7) << 4))) = pack4(xr[p]);
            }
        }

        // ---- 6. gates + bias + activation -> gt ----
        {
            v4f acc = ((ac0 + ac1) + (ac2 + ac3)) + ((xc0 + xc1) + (xc2 + xc3));
            float bcol = bs[w * 16 + r];
            #pragma unroll
            for (int rr = 0; rr < 4; ++rr) {
                float v = acc[rr] + bcol;
                float a = (w == 2) ? fast_tanh(v) : fast_sigmoid(v);
                gt[(w * 16 + (q * 4 + rr)) * 17 + r] = a;
            }
        }
        __syncthreads();   // (B) gt ready

        // ---- 7. pointwise c,h for (pb, jj); c in register ----
        float iv = gt[(0 * 16 + pb) * 17 + jj];
        float fv = gt[(1 * 16 + pb) * 17 + jj];
        float gv = gt[(2 * 16 + pb) * 17 + jj];
        float ov = gt[(3 * 16 + pb) * 17 + jj];
        float cn = fv * creg + iv * gv;
        creg = cn;
        float h = ov * fast_tanh(cn);

        if (t == T_ - 1) {
            out[(size_t)(tile * 16 + pb) * H_ + s * 16 + jj] = h;
            out[(size_t)B_ * H_ + (size_t)(tile * 16 + pb) * H_ + s * 16 + jj] = cn;
        } else {
            // ---- 8. EARLY POLLS for next step (slot t&1, target tag t).
            //         Issued BEFORE the publish store (order pinned below) so
            //         next step's pre-check waits vmcnt(1) — never our own
            //         store ack. Peers at-or-ahead land in these values. ----
            const u64* hbn = hbuf + (size_t)(t & 1) * 16384 + (size_t)tile * 4096;
            #pragma unroll
            for (int p = 0; p < 16; ++p)
                hv[p] = __hip_atomic_load(hbn + p * 256 + tid,
                            __ATOMIC_RELAXED, __HIP_MEMORY_SCOPE_AGENT);
            asm volatile("" ::: "memory");   // pin: polls issue before store

            // ---- 9. publish h_t: shfl-pair -> tagged u64, fire-and-forget --
            unsigned hu = (unsigned)f2bf(h);
            unsigned nb = (unsigned)__shfl_xor((int)hu, 1, 64);
            if ((jj & 1) == 0) {
                u64 pv = ((u64)(hu | (nb << 16)) << 32) | (u64)(unsigned)t;
                __hip_atomic_store(hbuf + (size_t)(t & 1) * 16384
                                        + (size_t)(tile * 16 + pb) * 256
                                        + s * 8 + (jj >> 1),
                                   pv, __ATOMIC_RELAXED, __HIP_MEMORY_SCOPE_AGENT);
            }
        }
    }
}

extern "C" void kernel_launch(void* const* d_in, const int* in_sizes, int n_in,
                              void* d_out, int out_size, void* d_ws, size_t ws_size,
                              hipStream_t stream) {
    const float* x  = (const float*)d_in[0];   // [64,2048,256]
    const float* W  = (const float*)d_in[1];   // [256,2048]
    const float* U  = (const float*)d_in[2];   // [512,2048]
    const float* bb = (const float*)d_in[3];   // [2048]
    float* out = (float*)d_out;                // [2][64][512] fp32 (h, c)

    u64* hbuf = (u64*)d_ws;                    // tagged u64[2][64][256] = 512KB

    // init tags to 0xFFFFFFFF (never equals any step t) — ws is poisoned 0xAA
    hipMemsetAsync(d_ws, 0xFF, (size_t)2 * 64 * 256 * 8, stream);

    hipFuncSetAttribute((const void*)lstm_persist,
                        hipFuncAttributeMaxDynamicSharedMemorySize, SMEM_BYTES);

    lstm_persist<<<TILES * 32, 256, SMEM_BYTES, stream>>>(
        x, W, U, bb, out, hbuf);
}

// Round 7
// 7762.128 us; speedup vs baseline: 1.1640x; 1.1640x over previous
//
#include <hip/hip_runtime.h>
#include <hip/hip_bf16.h>

// LSTM encoder: B=64, T=2048, D=256, H=512.
// Persistent-RNN: 128 wgs (1/CU, 160KB LDS), each owns a [768 x 64] bf16
// slice of [U;W] in LDS.
//
// Tagged-u64 dataflow sync (R5 scheme, verified 7396us): h exchanged as
// (bf16 h0|h1<<16)<<32 | step_tag u64 words; consumers poll the data words
// until tag == t-1 (the polling load IS the data load). Poll placement,
// spin structure, x-issue placement all R5-identical.
//
// ROUND-7 DELTA vs R5: remove barrier B + gt from the publish path.
//  - Column-split epilogue (R3's, correctness-proven): wave w owns h-cols
//    [s*16+w*4,+4) x all 4 gates; lane gate gi=(l&15)>>2, col cc=(l&15)&3.
//    Unified activation tanh(v)=2*sigmoid(2v)-1 per-lane; 3x shfl_xor(4/8/12)
//    gathers i,f,g,o; gi==0 lanes run pointwise and publish DIRECTLY after
//    their wave's MFMAs. One barrier (A) per step.
//  - hbuf goes COLUMN-major (word = col2*16 + row): each wave's column strip
//    is contiguous -> publish stays coalesced (128B per col2). Consumer poll
//    addresses unchanged; only the (row,col2) decode swaps.
//  - zh double-buffered [t&1] (+16KB): write(t+2,pre-A) vs read(t,post-A)
//    separated by barrier A(t+1). zx staging retargeted: stage x[t+2] into
//    zx[t&1] (the buffer consumed this step, post-A -> all waves' reads done);
//    next read at t+2 is behind A(t+1). x issue stays post-spin (R5).
//  - LDS refit: W-slabs (acc_x, spin-covered) at UWP=32; U-slabs keep UWP=40.
//    Total exactly 163840 B.

#define B_   64
#define T_   2048
#define D_   256
#define H_   512
#define G4   2048          // 4H
#define TILES 4            // B/16
#define UWPU 40            // U-slab row length (bf16), 32+8 pad (2-way reads)
#define UWPW 32            // W-slab row length (bf16), no pad (spin-covered)
#define BSTRU (64 * UWPU)  // U kk-slab stride (elems)
#define BSTRW (64 * UWPW)  // W kk-slab stride (elems)

#define OFF_UWU 0
#define SZ_UWU  (16 * 64 * UWPU * 2)         // 81920
#define OFF_UWW (OFF_UWU + SZ_UWU)           // 81920
#define SZ_UWW  (8 * 64 * UWPW * 2)          // 32768
#define OFF_ZH  (OFF_UWW + SZ_UWW)           // 114688
#define SZ_ZH   (2 * 16 * 1024)              // 32768 (h, dbuf, swizzled)
#define OFF_ZX  (OFF_ZH + SZ_ZH)             // 147456
#define SZ_ZX   (2 * 16 * 512)               // 16384 (x, dbuf, swizzled)
#define SMEM_BYTES (OFF_ZX + SZ_ZX)          // 163840 == 160 KiB cap

typedef __attribute__((ext_vector_type(8))) short v8s;
typedef __attribute__((ext_vector_type(4))) float v4f;
typedef unsigned long long u64;

__device__ __forceinline__ unsigned short f2bf(float f) {
    unsigned u = __builtin_bit_cast(unsigned, f);
    u = (u + 0x7FFFu + ((u >> 16) & 1u)) >> 16;   // RTNE
    return (unsigned short)u;
}
__device__ __forceinline__ u64 pack4(float4 v) {
    return (u64)((unsigned)f2bf(v.x) | ((unsigned)f2bf(v.y) << 16)) |
           ((u64)((unsigned)f2bf(v.z) | ((unsigned)f2bf(v.w) << 16)) << 32);
}
__device__ __forceinline__ float fast_tanh(float v) {
    float x = fminf(fmaxf(v, -15.0f), 15.0f);
    float e = __expf(2.0f * x);
    return (e - 1.0f) / (e + 1.0f);
}

__global__ void __launch_bounds__(256, 1)
lstm_persist(const float* __restrict__ x, const float* __restrict__ W,
             const float* __restrict__ U, const float* __restrict__ bias,
             float* __restrict__ out, u64* __restrict__ hbuf /* [2][4][256][16] */)
{
    extern __shared__ char smem[];
    unsigned short* UWU = (unsigned short*)(smem + OFF_UWU); // [16][64][UWPU]
    unsigned short* UWW = (unsigned short*)(smem + OFF_UWW); // [8][64][UWPW]
    char*           zhB = smem + OFF_ZH;                     // [2][16][1024B]
    char*           zxB = smem + OFF_ZX;                     // [2][16][512B]

    const int tid  = threadIdx.x;
    const int g    = blockIdx.x;
    const int tile = g & (TILES - 1);   // batch tile 0..3 (16 batches)
    const int s    = g >> 2;            // h-slice 0..31 (16 h-cols)
    const int l    = tid & 63;
    const int w    = tid >> 6;          // wave 0..3 == col-block
    const int bn   = l & 15;            // MFMA b-col within wave's 16
    const int gi   = bn >> 2;           // gate of this lane
    const int cc   = bn & 3;            // col within wave's 4 h-cols
    const int q4   = l >> 4;            // C/D row-quad & a-frag k-quad

    // ---- one-time: stage [U;W] slice (bf16) into LDS (split layout) ----
    for (int idx = tid; idx < (H_ + D_) * 64; idx += 256) {
        int k = idx >> 6;          // 0..767
        int n = idx & 63;          // local col: gate = n>>4, col = n&15
        int gcol = (n >> 4) * H_ + s * 16 + (n & 15);
        float v = (k < H_) ? U[(size_t)k * G4 + gcol]
                           : W[(size_t)(k - H_) * G4 + gcol];
        if (k < H_)
            UWU[((k >> 5) * 64 + n) * UWPU + (k & 31)] = f2bf(v);
        else
            UWW[(((k - H_) >> 5) * 64 + n) * UWPW + (k & 31)] = f2bf(v);
    }
    // per-lane bias + activation constants (gate gi, col w*4+cc)
    const float breg = bias[gi * H_ + s * 16 + w * 4 + cc];
    const bool  isG  = (gi == 2);
    const float oM = isG ? 2.0f : 1.0f;     // act = sigmoid(aM*v)*oM + oA
    const float oA = isG ? -1.0f : 0.0f;
    const float aM = isG ? 2.0f : 1.0f;

    // zero zh[0] for t=0
    for (int n = tid; n < 2048; n += 256)
        *(u64*)(zhB + n * 8) = 0ull;
    // stage x[0] -> zx[0], x[1] -> zx[1] (swizzled)
    #pragma unroll
    for (int p = 0; p < 4; ++p) {
        int n = p * 256 + tid, row = n >> 6, c4 = n & 63;
        int so = ((c4 * 8) ^ ((row & 7) << 4));
        float4 v0 = *(const float4*)(x + ((size_t)(tile * 16 + row) * T_ + 0) * D_ + c4 * 4);
        *(u64*)(zxB + row * 512 + so) = pack4(v0);
        float4 v1 = *(const float4*)(x + ((size_t)(tile * 16 + row) * T_ + 1) * D_ + c4 * 4);
        *(u64*)(zxB + 8192 + row * 512 + so) = pack4(v1);
    }

    // ---- per-lane fragment offsets (XOR-swizzle folded into bases) ----
    const int r    = bn;                 // a-frag row (batch)
    const int krot = (r >> 2) & 1;
    const int qx   = (q4 ^ (r & 3)) << 4;
    const int ahoff0 = r * 1024 + qx + 64 * krot;        // even kk
    const int ahoff1 = r * 1024 + qx + 64 * (krot ^ 1);  // odd kk
    const int axoff0 = r * 512  + qx + 64 * krot;
    const int axoff1 = r * 512  + qx + 64 * (krot ^ 1);
    const int gcl  = gi * 16 + w * 4 + cc;               // local b-col 0..63
    const unsigned short* browU = UWU + gcl * UWPU + q4 * 8;
    const unsigned short* browW = UWW + gcl * UWPW + q4 * 8;

    float creg[4] = {0.0f, 0.0f, 0.0f, 0.0f};
    __syncthreads();

    for (int t = 0; t < T_; ++t) {
        // ---- 1. issue tagged h_{t-1} poll loads ----
        u64 hv[16];
        u64* hb = hbuf + (size_t)((t - 1) & 1) * 16384 + (size_t)tile * 4096;
        if (t > 0) {
            #pragma unroll
            for (int p = 0; p < 16; ++p)
                hv[p] = __hip_atomic_load(hb + p * 256 + tid,
                                          __ATOMIC_RELAXED, __HIP_MEMORY_SCOPE_AGENT);
        }

        // ---- 2. acc_x = x_t @ Wslice (8 MFMAs, zx[t&1]; fills poll window) --
        const char* axb = zxB + (t & 1) * 8192;
        v4f xc0 = {0,0,0,0}, xc1 = {0,0,0,0}, xc2 = {0,0,0,0}, xc3 = {0,0,0,0};
        {
            v8s a0 = *(const v8s*)(axb + axoff0 + 0);
            v8s b0 = *(const v8s*)(browW + (size_t)0 * BSTRW);
            xc0 = __builtin_amdgcn_mfma_f32_16x16x32_bf16(a0, b0, xc0, 0, 0, 0);
            v8s a1 = *(const v8s*)(axb + axoff1 + 0);
            v8s b1 = *(const v8s*)(browW + (size_t)1 * BSTRW);
            xc1 = __builtin_amdgcn_mfma_f32_16x16x32_bf16(a1, b1, xc1, 0, 0, 0);
            v8s a2 = *(const v8s*)(axb + axoff0 + 128);
            v8s b2 = *(const v8s*)(browW + (size_t)2 * BSTRW);
            xc2 = __builtin_amdgcn_mfma_f32_16x16x32_bf16(a2, b2, xc2, 0, 0, 0);
            v8s a3 = *(const v8s*)(axb + axoff1 + 128);
            v8s b3 = *(const v8s*)(browW + (size_t)3 * BSTRW);
            xc3 = __builtin_amdgcn_mfma_f32_16x16x32_bf16(a3, b3, xc3, 0, 0, 0);
            v8s a4 = *(const v8s*)(axb + axoff0 + 256);
            v8s b4 = *(const v8s*)(browW + (size_t)4 * BSTRW);
            xc0 = __builtin_amdgcn_mfma_f32_16x16x32_bf16(a4, b4, xc0, 0, 0, 0);
            v8s a5 = *(const v8s*)(axb + axoff1 + 256);
            v8s b5 = *(const v8s*)(browW + (size_t)5 * BSTRW);
            xc1 = __builtin_amdgcn_mfma_f32_16x16x32_bf16(a5, b5, xc1, 0, 0, 0);
            v8s a6 = *(const v8s*)(axb + axoff0 + 384);
            v8s b6 = *(const v8s*)(browW + (size_t)6 * BSTRW);
            xc2 = __builtin_amdgcn_mfma_f32_16x16x32_bf16(a6, b6, xc2, 0, 0, 0);
            v8s a7 = *(const v8s*)(axb + axoff1 + 384);
            v8s b7 = *(const v8s*)(browW + (size_t)7 * BSTRW);
            xc3 = __builtin_amdgcn_mfma_f32_16x16x32_bf16(a7, b7, xc3, 0, 0, 0);
        }

        // ---- 3. tag check / re-poll pending; unpack -> zh[t&1] ----
        if (t > 0) {
            const unsigned tg = (unsigned)(t - 1);
            unsigned pend = 0u;
            #pragma unroll
            for (int p = 0; p < 16; ++p)
                pend |= ((unsigned)hv[p] != tg) ? (1u << p) : 0u;
            while (pend) {
                #pragma unroll
                for (int p = 0; p < 16; ++p)
                    if (pend & (1u << p))
                        hv[p] = __hip_atomic_load(hb + p * 256 + tid,
                                    __ATOMIC_RELAXED, __HIP_MEMORY_SCOPE_AGENT);
                unsigned np = 0u;
                #pragma unroll
                for (int p = 0; p < 16; ++p)
                    np |= ((unsigned)hv[p] != tg) ? (1u << p) : 0u;
                pend = np;
            }
            // col-major decode: word p*256+tid -> row = tid&15, col2 = p*16+(tid>>4)
            char* zht = zhB + (t & 1) * 16384;
            const int row = tid & 15;
            char* zrow = zht + row * 1024;
            const int swz = (row & 7) << 4;
            const int cb  = (tid >> 4) * 4;
            #pragma unroll
            for (int p = 0; p < 16; ++p) {
                *(unsigned*)(zrow + (((p * 64) + cb) ^ swz)) =
                    (unsigned)(hv[p] >> 32);
            }
        }

        // ---- 4. issue x[t+2] loads (post-spin; consumed at phase 6) ----
        float4 xr[4];
        if (t + 2 < T_) {
            #pragma unroll
            for (int p = 0; p < 4; ++p) {
                int n = p * 256 + tid, row = n >> 6, c4 = n & 63;
                xr[p] = *(const float4*)
                    (x + ((size_t)(tile * 16 + row) * T_ + (t + 2)) * D_ + c4 * 4);
            }
        }
        __syncthreads();   // (A) zh[t&1] ready; all phase-2 reads of zx[t&1] done

        // ---- 5. acc_h = h_{t-1} @ Uslice (16 MFMAs, zh[t&1]) ----
        const char* zht = zhB + (t & 1) * 16384;
        v4f ac0 = {0,0,0,0}, ac1 = {0,0,0,0}, ac2 = {0,0,0,0}, ac3 = {0,0,0,0};
        #pragma unroll
        for (int kk = 0; kk < 16; kk += 4) {
            v8s a0 = *(const v8s*)(zht + ahoff0 + 128 * (kk >> 1));
            v8s b0 = *(const v8s*)(browU + (size_t)(kk + 0) * BSTRU);
            ac0 = __builtin_amdgcn_mfma_f32_16x16x32_bf16(a0, b0, ac0, 0, 0, 0);
            v8s a1 = *(const v8s*)(zht + ahoff1 + 128 * (kk >> 1));
            v8s b1 = *(const v8s*)(browU + (size_t)(kk + 1) * BSTRU);
            ac1 = __builtin_amdgcn_mfma_f32_16x16x32_bf16(a1, b1, ac1, 0, 0, 0);
            v8s a2 = *(const v8s*)(zht + ahoff0 + 128 * (kk >> 1) + 128);
            v8s b2 = *(const v8s*)(browU + (size_t)(kk + 2) * BSTRU);
            ac2 = __builtin_amdgcn_mfma_f32_16x16x32_bf16(a2, b2, ac2, 0, 0, 0);
            v8s a3 = *(const v8s*)(zht + ahoff1 + 128 * (kk >> 1) + 128);
            v8s b3 = *(const v8s*)(browU + (size_t)(kk + 3) * BSTRU);
            ac3 = __builtin_amdgcn_mfma_f32_16x16x32_bf16(a3, b3, ac3, 0, 0, 0);
        }

        // ---- 6. stage x[t+2] -> zx[t&1] (buffer consumed at phase 2;
        //         all waves' reads ordered before us by barrier A) ----
        if (t + 2 < T_) {
            char* zxn = zxB + (t & 1) * 8192;
            #pragma unroll
            for (int p = 0; p < 4; ++p) {
                int n = p * 256 + tid, row = n >> 6, c4 = n & 63;
                *(u64*)(zxn + row * 512 + ((c4 * 8) ^ ((row & 7) << 4))) = pack4(xr[p]);
            }
        }

        // ---- 7. per-wave epilogue: bias + unified activation + gather ----
        v4f acc = ((ac0 + ac1) + (ac2 + ac3)) + ((xc0 + xc1) + (xc2 + xc3));
        float hval[4], cnl[4];
        #pragma unroll
        for (int rr = 0; rr < 4; ++rr) {
            float v = acc[rr] + breg;
            float e = __expf(-aM * v);
            float sg = 1.0f / (1.0f + e);
            float a  = sg * oM + oA;              // own gate's activation
            float fA = __shfl_xor(a, 4, 64);      // gate gi^1
            float gA = __shfl_xor(a, 8, 64);      // gate gi^2
            float oV = __shfl_xor(a, 12, 64);     // gate gi^3
            // valid on gi==0 lanes: a=i, fA=f, gA=g, oV=o
            float cn = fA * creg[rr] + a * gA;
            creg[rr] = cn;
            cnl[rr]  = cn;
            hval[rr] = oV * fast_tanh(cn);
        }

        if (t == T_ - 1) {
            if (gi == 0) {
                #pragma unroll
                for (int rr = 0; rr < 4; ++rr) {
                    int grow = tile * 16 + q4 * 4 + rr;
                    int col  = s * 16 + w * 4 + cc;
                    out[(size_t)grow * H_ + col] = hval[rr];
                    out[(size_t)B_ * H_ + (size_t)grow * H_ + col] = cnl[rr];
                }
            }
        } else {
            // ---- 8. publish (per-wave, no barrier): pair cc via shfl,
            //         col-major hbuf -> 4 consecutive u64 per lane ----
            unsigned pk[4];
            #pragma unroll
            for (int rr = 0; rr < 4; ++rr) {
                unsigned hu = (unsigned)f2bf(hval[rr]);
                unsigned nb = (unsigned)__shfl_xor((int)hu, 1, 64);
                pk[rr] = hu | (nb << 16);
            }
            if (gi == 0 && (cc & 1) == 0) {
                int col2 = s * 8 + w * 2 + (cc >> 1);
                u64* hbw = hbuf + (size_t)(t & 1) * 16384 + (size_t)tile * 4096
                         + (size_t)col2 * 16 + q4 * 4;
                #pragma unroll
                for (int rr = 0; rr < 4; ++rr) {
                    __hip_atomic_store(hbw + rr,
                                       ((u64)pk[rr] << 32) | (u64)(unsigned)t,
                                       __ATOMIC_RELAXED, __HIP_MEMORY_SCOPE_AGENT);
                }
            }
        }
    }
}

extern "C" void kernel_launch(void* const* d_in, const int* in_sizes, int n_in,
                              void* d_out, int out_size, void* d_ws, size_t ws_size,
                              hipStream_t stream) {
    const float* x  = (const float*)d_in[0];   // [64,2048,256]
    const float* W  = (const float*)d_in[1];   // [256,2048]
    const float* U  = (const float*)d_in[2];   // [512,2048]
    const float* bb = (const float*)d_in[3];   // [2048]
    float* out = (float*)d_out;                // [2][64][512] fp32 (h, c)

    u64* hbuf = (u64*)d_ws;                    // tagged u64[2][4][256][16] = 512KB

    // init tags to 0xFFFFFFFF (never equals any step t) — ws is poisoned 0xAA
    hipMemsetAsync(d_ws, 0xFF, (size_t)2 * 64 * 256 * 8, stream);

    hipFuncSetAttribute((const void*)lstm_persist,
                        hipFuncAttributeMaxDynamicSharedMemorySize, SMEM_BYTES);

    lstm_persist<<<TILES * 32, 256, SMEM_BYTES, stream>>>(
        x, W, U, bb, out, hbuf);
}